// Round 14
// baseline (30.278 us; speedup 1.0000x reference)
//
#include <hip/hip_runtime.h>

#define H 128
#define W 128
#define Zd 16
#define C 20
#define HWZ (H * W * Zd)   // 262144 spatial positions

#define NXCD 8
#define CPGF2 10           // channels per block in yz (2 channel-groups)

typedef float f4 __attribute__((ext_vector_type(4)));

__device__ __forceinline__ f4 load4(const float* p) { return *(const f4*)p; }

// DPP lane shifts (16-lane rows). Boundary lanes get 0; safe because any lane
// where the shifted value is garbage has z4==0/12 and its gate coeff is zeroed.
__device__ __forceinline__ float dpp_prev(float x) {  // lane i <- lane i-1
    int r = __builtin_amdgcn_update_dpp(0, __builtin_bit_cast(int, x), 0x111, 0xF, 0xF, false);
    return __builtin_bit_cast(float, r);
}
__device__ __forceinline__ float dpp_next(float x) {  // lane i <- lane i+1
    int r = __builtin_amdgcn_update_dpp(0, __builtin_bit_cast(int, x), 0x101, 0xF, 0xF, false);
    return __builtin_bit_cast(float, r);
}

__device__ __forceinline__ int iclamp(int v, int lo, int hi) {
    return v < lo ? lo : (v > hi ? hi : v);
}

// ---------------- X step with LDS tap staging.
// Block = 256 threads = one (cg, h, w-half): 64 w x 4 z4. Per channel, the
// 3 input rows (h-1,h,h+1) x 66 w (with +-1 halo) are staged into LDS once
// (3.1 f4 global loads/thread) and the 9 taps read from LDS -> cuts the
// dominant L2 tap traffic ~2.9x. z-dim padded 16->20 floats: consume/stage
// access is 2-way bank aliased max (free).
// grid = 1024: xcd=bid&7 owns rows [16x,16x+16) for all 4 cgroups.
#define XW 66              // staged w extent (64 + 2 halo)
#define XZP 20             // padded z stride (floats)
#define XSTG (3 * XW * 4)  // 792 f4 stage elements per channel
__global__ __launch_bounds__(256) void prop_x(const float* __restrict__ gd,
                                              const float* __restrict__ in,
                                              float* __restrict__ out) {
    const int bid = blockIdx.x;
    const int xcd = bid & (NXCD - 1);
    const int i = bid >> 3;              // 0..127
    const int cg = i >> 5;               // 0..3
    const int pb = (xcd << 5) + (i & 31);
    const int h = pb >> 1;               // xcd*16 + ...
    const int wbase = (pb & 1) << 6;     // 0 or 64

    const int t = threadIdx.x;
    const int z4 = (t & 3) << 2;
    const int ww = t >> 2;               // local w 0..63
    const int w = wbase + ww;

    __shared__ float xs[3 * XW * XZP];   // 15.8 KB

    const int DI[8] = {1, 1, 1, 0, 0, -1, -1, -1};
    const int DJ[8] = {1, 0, -1, 1, -1, 1, 0, -1};

    // gates for own position (8 global f4 + normalize), kept in registers
    f4 g[8];
    f4 A = {0, 0, 0, 0}, S = {0, 0, 0, 0};
#pragma unroll
    for (int k = 0; k < 8; ++k) {
        int hh = h + DI[k], wwg = w + DJ[k];
        bool valid = ((unsigned)hh < H) && ((unsigned)wwg < W);
        f4 val = {0, 0, 0, 0};
        if (valid) val = load4(gd + ((k * H + hh) * W + wwg) * Zd + z4);
        g[k] = val;
#pragma unroll
        for (int e = 0; e < 4; ++e) A[e] += __builtin_fabsf(val[e]);
        S += val;
    }
    f4 invA = 1.0f / A;
    f4 c0 = 1.0f - S * invA;
#pragma unroll
    for (int k = 0; k < 8; ++k) g[k] *= invA;

    const int base = (h * W + w) * Zd + z4;
    const int ctr = (XW + ww + 1) * XZP + z4;  // LDS float-offset of own center

#pragma unroll 1
    for (int cc = 0; cc < 5; ++cc) {
        const int c = cg * 5 + cc;
        const float* pc = in + c * HWZ;

        __syncthreads();   // previous channel's consume done
        // stage rows h-1,h,h+1 x [wbase-1, wbase+64] (clamped; gate=0 covers edges)
#pragma unroll
        for (int s0 = 0; s0 < XSTG; s0 += 256) {
            int s = s0 + t;
            if (s < XSTG) {
                int r = s / (XW * 4);
                int rem = s - r * (XW * 4);
                int wi = rem >> 2;
                int zq = (rem & 3) << 2;
                int gh = iclamp(h + r - 1, 0, H - 1);
                int gw = iclamp(wbase - 1 + wi, 0, W - 1);
                f4 v = load4(pc + (gh * W + gw) * Zd + zq);
                *(f4*)(&xs[(r * XW + wi) * XZP + zq]) = v;
            }
        }
        __syncthreads();

        f4 acc = c0 * load4(&xs[ctr]);
#pragma unroll
        for (int k = 0; k < 8; ++k)
            acc += g[k] * load4(&xs[ctr + DI[k] * (XW * XZP) + DJ[k] * XZP]);
        *(f4*)(out + c * HWZ + base) = acc;
    }
}

// ---------------- Fused Y+Z with DPP z-shifts (exact R12 version): one block =
// one h-row x 10 channels; yout in DYNAMIC LDS (80 KB f32).
// grid = 256: xcd(8) x cgf(2) x row(16).
__global__ __launch_bounds__(512) void prop_yz(const float* __restrict__ gd,
                                               const float* __restrict__ in,
                                               float* __restrict__ out) {
    extern __shared__ float yout[];   // [CPGF2][W][Zd] = 80 KB

    const int bid = blockIdx.x;
    const int xcd = bid & (NXCD - 1);
    const int i = bid >> 3;     // 0..31
    const int cgf = i >> 4;     // 0..1
    const int h = (xcd << 4) + (i & 15);

    const int t = threadIdx.x;  // 0..511
    const int z4 = (t & 3) << 2;
    const int w = t >> 2;       // 0..127

    const int DI[8] = {1, 1, 1, 0, 0, -1, -1, -1};
    const int DJ[8] = {1, 0, -1, 1, -1, 1, 0, -1};
    const int base = (h * W + w) * Zd + z4;

    // ======== Y step (gates 8..15, row = h, row stride W*Zd) ========
    {
        const int gbase = (((8 * H) + h) * W + w) * Zd + z4;
        f4 g[8];
        f4 A = {0, 0, 0, 0}, S = {0, 0, 0, 0};
#pragma unroll
        for (int k = 0; k < 8; ++k) {
            int di = DI[k], dj = DJ[k];
            bool rv = (unsigned)(h + di) < H;
            f4 va = {0, 0, 0, 0};
            if (rv) va = load4(gd + gbase + k * HWZ + di * (W * Zd));
            f4 val;
            if (dj == 0) {
                val = va;
            } else if (dj == -1) {
                val = (f4){dpp_prev(va[3]), va[0], va[1], va[2]};
                if (z4 == 0) val[0] = 0.f;
            } else {
                val = (f4){va[1], va[2], va[3], dpp_next(va[0])};
                if (z4 == 12) val[3] = 0.f;
            }
            g[k] = val;
#pragma unroll
            for (int e = 0; e < 4; ++e) A[e] += __builtin_fabsf(val[e]);
            S += val;
        }
        f4 invA = 1.0f / A;
        f4 c0 = 1.0f - S * invA;
#pragma unroll
        for (int k = 0; k < 8; ++k) g[k] *= invA;

        f4 gp[3] = {g[0], g[3], g[5]};   // dj=+1 per row {di=+1,0,-1}
        f4 gc[3] = {g[1], c0, g[6]};
        f4 gm[3] = {g[2], g[4], g[7]};
        const int DIr[3] = {1, 0, -1};
        int rowoff[3];
#pragma unroll
        for (int r = 0; r < 3; ++r)
            rowoff[r] = ((unsigned)(h + DIr[r]) < H) ? DIr[r] * (W * Zd) : 0;

#pragma unroll 2
        for (int cc = 0; cc < CPGF2; ++cc) {
            const int c = cgf * CPGF2 + cc;
            const float* pc = in + c * HWZ + base;
            f4 acc = {0, 0, 0, 0};
#pragma unroll
            for (int r = 0; r < 3; ++r) {
                f4 v = load4(pc + rowoff[r]);
                float lo = dpp_prev(v[3]);
                float hi = dpp_next(v[0]);
                acc += gm[r] * (f4){lo, v[0], v[1], v[2]} + gc[r] * v +
                       gp[r] * (f4){v[1], v[2], v[3], hi};
            }
            *(f4*)(&yout[(cc * W + w) * Zd + z4]) = acc;
        }
    }

    __syncthreads();

    // ======== Z step (gates 16..23, row = w, row stride Zd, taps from LDS) ========
    {
        const int gbase = (((16 * H) + h) * W + w) * Zd + z4;
        f4 g[8];
        f4 A = {0, 0, 0, 0}, S = {0, 0, 0, 0};
#pragma unroll
        for (int k = 0; k < 8; ++k) {
            int di = DI[k], dj = DJ[k];
            bool rv = (unsigned)(w + di) < W;
            f4 va = {0, 0, 0, 0};
            if (rv) va = load4(gd + gbase + k * HWZ + di * Zd);
            f4 val;
            if (dj == 0) {
                val = va;
            } else if (dj == -1) {
                val = (f4){dpp_prev(va[3]), va[0], va[1], va[2]};
                if (z4 == 0) val[0] = 0.f;
            } else {
                val = (f4){va[1], va[2], va[3], dpp_next(va[0])};
                if (z4 == 12) val[3] = 0.f;
            }
            g[k] = val;
#pragma unroll
            for (int e = 0; e < 4; ++e) A[e] += __builtin_fabsf(val[e]);
            S += val;
        }
        f4 invA = 1.0f / A;
        f4 c0 = 1.0f - S * invA;
#pragma unroll
        for (int k = 0; k < 8; ++k) g[k] *= invA;

        f4 gp[3] = {g[0], g[3], g[5]};
        f4 gc[3] = {g[1], c0, g[6]};
        f4 gm[3] = {g[2], g[4], g[7]};
        const int DIr[3] = {1, 0, -1};
        int woff[3];  // LDS float offset for row w+di
#pragma unroll
        for (int r = 0; r < 3; ++r)
            woff[r] = ((unsigned)(w + DIr[r]) < W) ? DIr[r] * Zd : 0;

#pragma unroll 2
        for (int cc = 0; cc < CPGF2; ++cc) {
            const int c = cgf * CPGF2 + cc;
            const float* pl = &yout[(cc * W + w) * Zd + z4];
            f4 acc = {0, 0, 0, 0};
#pragma unroll
            for (int r = 0; r < 3; ++r) {
                f4 v = load4(pl + woff[r]);
                float lo = dpp_prev(v[3]);
                float hi = dpp_next(v[0]);
                acc += gm[r] * (f4){lo, v[0], v[1], v[2]} + gc[r] * v +
                       gp[r] * (f4){v[1], v[2], v[3], hi};
            }
            *(f4*)(out + c * HWZ + base) = acc;
        }
    }
}

extern "C" void kernel_launch(void* const* d_in, const int* in_sizes, int n_in,
                              void* d_out, int out_size, void* d_ws, size_t ws_size,
                              hipStream_t stream) {
    const float* gd = (const float*)d_in[0];   // guidance (24,128,128,16) f32
    const float* blur = (const float*)d_in[1]; // blur (20,128,128,16) f32
    float* out = (float*)d_out;                // (20,128,128,16) f32
    float* ws = (float*)d_ws;

    const size_t yz_lds = (size_t)CPGF2 * W * Zd * sizeof(float);  // 80 KB
    hipFuncSetAttribute((const void*)prop_yz,
                        hipFuncAttributeMaxDynamicSharedMemorySize, (int)yz_lds);

    prop_x<<<dim3(1024), dim3(256), 0, stream>>>(gd, blur, ws);      // X: blur -> ws
    prop_yz<<<dim3(256), dim3(512), yz_lds, stream>>>(gd, ws, out);  // Y+Z: ws -> out
}